// Round 2
// baseline (852.422 us; speedup 1.0000x reference)
//
#include <hip/hip_runtime.h>
#include <hip/hip_bf16.h>

typedef __attribute__((ext_vector_type(8))) short short8_t;
typedef __attribute__((ext_vector_type(8))) __bf16 bf16x8;
typedef __attribute__((ext_vector_type(4))) float f32x4;

__device__ __forceinline__ void gload16(const void* g, void* l) {
  __builtin_amdgcn_global_load_lds(
      (const __attribute__((address_space(1))) void*)g,
      (__attribute__((address_space(3))) void*)l, 16, 0, 0);
}

__device__ __forceinline__ unsigned short f2bf(float f) {
  __hip_bfloat16 h = __float2bfloat16(f);
  return __builtin_bit_cast(unsigned short, h);
}

// ---------------- conversion kernels ----------------

__global__ void k_cvt_feat(const float* __restrict__ in, unsigned short* __restrict__ out) {
  const size_t N = (size_t)4096 * 8192;
  size_t i = ((size_t)blockIdx.x * 256 + threadIdx.x) * 4;
  const size_t stride = (size_t)gridDim.x * 256 * 4;
  for (; i < N; i += stride) {
    float4 v = *(const float4*)(in + i);
    ushort4 o;
    o.x = f2bf(v.x); o.y = f2bf(v.y); o.z = f2bf(v.z); o.w = f2bf(v.w);
    *(ushort4*)(out + i) = o;
  }
}

// W1 f32 [p][8192][256] -> bf16 transposed chunk-local [z][256][8192]
__global__ void k_cvt_w1(const float* __restrict__ W1, unsigned short* __restrict__ out, int p0) {
  __shared__ unsigned short t[64][66];
  const int p = p0 + blockIdx.z;
  const float* src = W1 + (size_t)p * 8192 * 256;
  unsigned short* dst = out + (size_t)blockIdx.z * 256 * 8192;
  const int f0 = blockIdx.x * 64, h0 = blockIdx.y * 64;
#pragma unroll
  for (int i = 0; i < 16; ++i) {
    int tt = i * 256 + threadIdx.x;
    int r = tt >> 6, c = tt & 63;
    t[r][c] = f2bf(src[(size_t)(f0 + r) * 256 + h0 + c]);
  }
  __syncthreads();
#pragma unroll
  for (int i = 0; i < 16; ++i) {
    int tt = i * 256 + threadIdx.x;
    int r = tt >> 6, c = tt & 63;
    dst[(size_t)(h0 + r) * 8192 + f0 + c] = t[c][r];
  }
}

// W2 f32 [p][256][128] -> bf16 transposed [p][128][256]
__global__ void k_cvt_w2(const float* __restrict__ W2, unsigned short* __restrict__ out) {
  const int p = blockIdx.x;
  const float* src = W2 + (size_t)p * 256 * 128;
  unsigned short* dst = out + (size_t)p * 128 * 256;
  for (int tt = threadIdx.x; tt < 128 * 256; tt += 256) {
    int j = tt >> 8, h = tt & 255;
    dst[tt] = f2bf(src[(size_t)h * 128 + j]);
  }
}

// ---------------- GEMM1: h1 = relu(features @ W1 + b1) ----------------
// 256x256 tile, BK=32, 8 waves (2Mx4N, per-wave 128x64), 4-deep LDS ring,
// 2 phases/K-tile, counted vmcnt(8), setprio around MFMA, XCD swizzle.
// LDS buf layout: 256 rows x 32 bf16 (64B = 4 units of 16B); unit t of row r
// holds global unit t ^ ((r>>1)&3)  (bank-conflict-free for the frag reads).
__global__ __launch_bounds__(512, 2) void k_gemm1(
    const unsigned short* __restrict__ A,    // [4096][8192] bf16
    const unsigned short* __restrict__ Bt,   // [z][256][8192] bf16
    const float* __restrict__ b1,
    unsigned short* __restrict__ h1,
    int p0) {
  __shared__ __align__(16) unsigned short SA[4 * 8192];  // 64 KiB
  __shared__ __align__(16) unsigned short SB[4 * 8192];  // 64 KiB

  const int tid = threadIdx.x;
  const int lane = tid & 63;
  const int wave = tid >> 6;
  const int wm = wave >> 2;        // 0..1  (M half)
  const int wn = wave & 3;         // 0..3  (N quarter)

  // bijective XCD swizzle: consecutive logical tiles (p-major) per XCD
  const int nwg = gridDim.x * gridDim.y;
  const int orig = blockIdx.y * gridDim.x + blockIdx.x;
  const int q = nwg >> 3, r_ = nwg & 7;
  const int xcd = orig & 7, idx = orig >> 3;
  const int wg = (xcd < r_ ? xcd * (q + 1) : r_ * (q + 1) + (xcd - r_) * q) + idx;
  const int mx = wg & 15;          // gridDim.x == 16
  const int z = wg >> 4;
  const int p = p0 + z;
  const int m0 = mx * 256;

  const unsigned short* Ab = A + (size_t)m0 * 8192;
  const unsigned short* Bb = Bt + (size_t)z * 256 * 8192;

  // staging: per K-tile 1024 units of 16B per matrix; 2 loads/thread each.
  // element e = i*512 + tid; row r = e>>2; phys unit = e&3; global unit u = (e&3)^((r>>1)&3)
  const unsigned short* pA0; const unsigned short* pA1;
  const unsigned short* pB0; const unsigned short* pB1;
  {
    int e0 = tid,        r0 = e0 >> 2, u0 = (e0 & 3) ^ ((r0 >> 1) & 3);
    int e1 = 512 + tid,  r1 = e1 >> 2, u1 = (e1 & 3) ^ ((r1 >> 1) & 3);
    pA0 = Ab + (size_t)r0 * 8192 + u0 * 8;
    pA1 = Ab + (size_t)r1 * 8192 + u1 * 8;
    pB0 = Bb + (size_t)r0 * 8192 + u0 * 8;
    pB1 = Bb + (size_t)r1 * 8192 + u1 * 8;
  }
  const int lao0 = (wave * 64) * 8;          // LDS short-offsets (wave-uniform)
  const int lao1 = (512 + wave * 64) * 8;

  // frag read offsets (shorts): row*32 + (ku ^ ((row>>1)&3))*8, ku = lane>>4
  const int arow = wm * 128 + (lane & 15);
  const int brow = wn * 64 + (lane & 15);
  const int a_off0 = arow * 32 + ((((arow >> 1) & 3) ^ (lane >> 4)) * 8);
  const int b_off0 = brow * 32 + ((((brow >> 1) & 3) ^ (lane >> 4)) * 8);

  f32x4 acc[8][4] = {};

  const int NT = 8192 / 32;  // 256 K-tiles

  auto stageA = [&](int T) {
    const int k0 = T * 32, cb = T & 3;
    gload16(pA0 + k0, SA + cb * 8192 + lao0);
    gload16(pA1 + k0, SA + cb * 8192 + lao1);
  };
  auto stageB = [&](int T) {
    const int k0 = T * 32, cb = T & 3;
    gload16(pB0 + k0, SB + cb * 8192 + lao0);
    gload16(pB1 + k0, SB + cb * 8192 + lao1);
  };

  auto kstep = [&](int T, bool PF, int VM) {
    const int cb = T & 3;
    const unsigned short* sa = SA + cb * 8192;
    const unsigned short* sb = SB + cb * 8192;
    bf16x8 bfr[4], afr[4];
#pragma unroll
    for (int nj = 0; nj < 4; ++nj) bfr[nj] = __builtin_bit_cast(bf16x8, *(const short8_t*)(sb + b_off0 + nj * 512));
#pragma unroll
    for (int mi = 0; mi < 4; ++mi) afr[mi] = __builtin_bit_cast(bf16x8, *(const short8_t*)(sa + a_off0 + mi * 512));
    if (PF) stageA(T + 3);
    __builtin_amdgcn_s_barrier();
    asm volatile("s_waitcnt lgkmcnt(0)" ::: "memory");
    __builtin_amdgcn_sched_barrier(0);
    __builtin_amdgcn_s_setprio(1);
#pragma unroll
    for (int mi = 0; mi < 4; ++mi)
#pragma unroll
      for (int nj = 0; nj < 4; ++nj)
        acc[mi][nj] = __builtin_amdgcn_mfma_f32_16x16x32_bf16(afr[mi], bfr[nj], acc[mi][nj], 0, 0, 0);
    __builtin_amdgcn_s_setprio(0);
    __builtin_amdgcn_s_barrier();
    __builtin_amdgcn_sched_barrier(0);
#pragma unroll
    for (int mi = 0; mi < 4; ++mi) afr[mi] = __builtin_bit_cast(bf16x8, *(const short8_t*)(sa + a_off0 + (mi + 4) * 512));
    if (PF) stageB(T + 3);
    __builtin_amdgcn_s_barrier();
    asm volatile("s_waitcnt lgkmcnt(0)" ::: "memory");
    __builtin_amdgcn_sched_barrier(0);
    __builtin_amdgcn_s_setprio(1);
#pragma unroll
    for (int mi = 0; mi < 4; ++mi)
#pragma unroll
      for (int nj = 0; nj < 4; ++nj)
        acc[mi + 4][nj] = __builtin_amdgcn_mfma_f32_16x16x32_bf16(afr[mi], bfr[nj], acc[mi + 4][nj], 0, 0, 0);
    __builtin_amdgcn_s_setprio(0);
    if (VM == 8)      asm volatile("s_waitcnt vmcnt(8)" ::: "memory");
    else if (VM == 4) asm volatile("s_waitcnt vmcnt(4)" ::: "memory");
    else if (VM == 0) asm volatile("s_waitcnt vmcnt(0)" ::: "memory");
    __builtin_amdgcn_s_barrier();
    __builtin_amdgcn_sched_barrier(0);
  };

  // prologue: stage tiles 0,1,2 (12 loads); wait tile 0 (leave 8 in flight)
  stageA(0); stageB(0); stageA(1); stageB(1); stageA(2); stageB(2);
  asm volatile("s_waitcnt vmcnt(8)" ::: "memory");
  __builtin_amdgcn_s_barrier();
  __builtin_amdgcn_sched_barrier(0);

  for (int t = 0; t < NT - 3; ++t) kstep(t, true, 8);
  kstep(NT - 3, false, 4);
  kstep(NT - 2, false, 0);
  kstep(NT - 1, false, -1);

  // epilogue: + b1, relu, h1 bf16 [p][4096][256]
  const int rg = lane >> 4, c16 = lane & 15;
#pragma unroll
  for (int nj = 0; nj < 4; ++nj) {
    const int col = wn * 64 + nj * 16 + c16;
    const float bb = b1[p * 256 + col];
#pragma unroll
    for (int mi = 0; mi < 8; ++mi) {
      const int rbase = m0 + wm * 128 + mi * 16 + rg * 4;
#pragma unroll
      for (int rr = 0; rr < 4; ++rr) {
        float v = acc[mi][nj][rr] + bb;
        v = v > 0.f ? v : 0.f;
        h1[((size_t)p * 4096 + rbase + rr) * 256 + col] = f2bf(v);
      }
    }
  }
}

// ---------------- GEMM2+3 fused ----------------
__global__ __launch_bounds__(256, 2) void k_gemm23(
    const unsigned short* __restrict__ h1,   // [29][4096][256] bf16
    const unsigned short* __restrict__ W2t,  // [29][128][256] bf16
    const float* __restrict__ b2,
    const float* __restrict__ W3,
    const float* __restrict__ b3,
    float* __restrict__ out) {               // [4096][29]
  __shared__ __align__(16) unsigned short lds_a[128 * 64];
  __shared__ __align__(16) unsigned short lds_b[128 * 64];
  const int tid = threadIdx.x;
  const int lane = tid & 63;
  const int wave = tid >> 6;
  const int m0 = blockIdx.x * 128;
  const int p = blockIdx.y;

  const unsigned short* Ab = h1 + ((size_t)p * 4096 + m0) * 256;
  const unsigned short* Bb = W2t + (size_t)p * 128 * 256;

  f32x4 acc[2][8] = {};

  for (int k0 = 0; k0 < 256; k0 += 64) {
    __syncthreads();
#pragma unroll
    for (int i = 0; i < 4; ++i) {
      int t = i * 256 + tid;
      int r = t >> 3;
      int uu = (t & 7) ^ (r & 7);
      gload16(Ab + (size_t)r * 256 + k0 + uu * 8, &lds_a[(i * 256 + wave * 64) * 8]);
      gload16(Bb + (size_t)r * 256 + k0 + uu * 8, &lds_b[(i * 256 + wave * 64) * 8]);
    }
    __syncthreads();
#pragma unroll
    for (int kk = 0; kk < 64; kk += 32) {
      const int ku = (kk >> 3) + (lane >> 4);
      bf16x8 af[2], bfv[8];
#pragma unroll
      for (int mi = 0; mi < 2; ++mi) {
        int row = wave * 32 + mi * 16 + (lane & 15);
        int u = ku ^ (row & 7);
        af[mi] = __builtin_bit_cast(bf16x8, *(const short8_t*)&lds_a[row * 64 + u * 8]);
      }
#pragma unroll
      for (int nj = 0; nj < 8; ++nj) {
        int row = nj * 16 + (lane & 15);
        int u = ku ^ (row & 7);
        bfv[nj] = __builtin_bit_cast(bf16x8, *(const short8_t*)&lds_b[row * 64 + u * 8]);
      }
#pragma unroll
      for (int mi = 0; mi < 2; ++mi)
#pragma unroll
        for (int nj = 0; nj < 8; ++nj)
          acc[mi][nj] = __builtin_amdgcn_mfma_f32_16x16x32_bf16(af[mi], bfv[nj], acc[mi][nj], 0, 0, 0);
    }
  }

  float b2v[8], w3v[8];
  const int c16 = lane & 15;
#pragma unroll
  for (int nj = 0; nj < 8; ++nj) {
    int c = nj * 16 + c16;
    b2v[nj] = b2[p * 128 + c];
    w3v[nj] = W3[p * 128 + c];
  }
  const float b3p = b3[p];
#pragma unroll
  for (int mi = 0; mi < 2; ++mi) {
#pragma unroll
    for (int r = 0; r < 4; ++r) {
      float s = 0.f;
#pragma unroll
      for (int nj = 0; nj < 8; ++nj) {
        float v = acc[mi][nj][r] + b2v[nj];
        v = v > 0.f ? v : 0.f;
        s += v * w3v[nj];
      }
      s += __shfl_xor(s, 1);
      s += __shfl_xor(s, 2);
      s += __shfl_xor(s, 4);
      s += __shfl_xor(s, 8);
      if ((lane & 15) == 0) {
        int m = m0 + wave * 32 + mi * 16 + (lane >> 4) * 4 + r;
        float logit = s + b3p;
        out[(size_t)m * 29 + p] = 1.f / (1.f + __expf(-logit));
      }
    }
  }
}

// ---------------- launch ----------------
extern "C" void kernel_launch(void* const* d_in, const int* in_sizes, int n_in,
                              void* d_out, int out_size, void* d_ws, size_t ws_size,
                              hipStream_t stream) {
  const float* features = (const float*)d_in[0];
  const float* W1 = (const float*)d_in[1];
  const float* b1 = (const float*)d_in[2];
  const float* W2 = (const float*)d_in[3];
  const float* b2 = (const float*)d_in[4];
  const float* W3 = (const float*)d_in[5];
  const float* b3 = (const float*)d_in[6];
  float* out = (float*)d_out;

  char* ws = (char*)d_ws;
  const size_t featB = (size_t)4096 * 8192 * 2;       // 64 MB
  const size_t h1B   = (size_t)29 * 4096 * 256 * 2;   // 58 MB
  const size_t w2B   = (size_t)29 * 128 * 256 * 2;    // 1.9 MB
  const size_t w1pp  = (size_t)256 * 8192 * 2;        // 4 MB per predicate

  unsigned short* featbf = (unsigned short*)ws;
  unsigned short* h1bf   = (unsigned short*)(ws + featB);
  unsigned short* w2t    = (unsigned short*)(ws + featB + h1B);
  unsigned short* w1t    = (unsigned short*)(ws + featB + h1B + w2B);

  size_t base = featB + h1B + w2B;
  size_t rem = (ws_size > base) ? (ws_size - base) : 0;
  int CH = (int)(rem / w1pp);
  if (CH > 29) CH = 29;
  if (CH < 1) CH = 1;

  k_cvt_feat<<<2048, 256, 0, stream>>>(features, featbf);
  k_cvt_w2<<<29, 256, 0, stream>>>(W2, w2t);

  for (int p0 = 0; p0 < 29; p0 += CH) {
    int c = (29 - p0) < CH ? (29 - p0) : CH;
    k_cvt_w1<<<dim3(128, 4, c), 256, 0, stream>>>(W1, w1t, p0);
    k_gemm1<<<dim3(16, c), 512, 0, stream>>>(featbf, w1t, b1, h1bf, p0);
  }

  k_gemm23<<<dim3(32, 29), 256, 0, stream>>>(h1bf, w2t, b2, W3, b3, out);
}

// Round 3
// 614.096 us; speedup vs baseline: 1.3881x; 1.3881x over previous
//
#include <hip/hip_runtime.h>
#include <hip/hip_bf16.h>

typedef __attribute__((ext_vector_type(8))) short short8_t;
typedef __attribute__((ext_vector_type(8))) __bf16 bf16x8;
typedef __attribute__((ext_vector_type(4))) float f32x4;

__device__ __forceinline__ void gload16(const void* g, void* l) {
  __builtin_amdgcn_global_load_lds(
      (const __attribute__((address_space(1))) void*)g,
      (__attribute__((address_space(3))) void*)l, 16, 0, 0);
}

__device__ __forceinline__ unsigned short f2bf(float f) {
  __hip_bfloat16 h = __float2bfloat16(f);
  return __builtin_bit_cast(unsigned short, h);
}

#define BARRIER() asm volatile("s_barrier" ::: "memory")

// ---------------- conversion kernels ----------------

__global__ void k_cvt_feat(const float* __restrict__ in, unsigned short* __restrict__ out) {
  const size_t N = (size_t)4096 * 8192;
  size_t i = ((size_t)blockIdx.x * 256 + threadIdx.x) * 4;
  const size_t stride = (size_t)gridDim.x * 256 * 4;
  for (; i < N; i += stride) {
    float4 v = *(const float4*)(in + i);
    ushort4 o;
    o.x = f2bf(v.x); o.y = f2bf(v.y); o.z = f2bf(v.z); o.w = f2bf(v.w);
    *(ushort4*)(out + i) = o;
  }
}

// W1 f32 [p][8192][256] -> bf16 transposed chunk-local [z][256][8192]
__global__ void k_cvt_w1(const float* __restrict__ W1, unsigned short* __restrict__ out, int p0) {
  __shared__ unsigned short t[64][66];
  const int p = p0 + blockIdx.z;
  const float* src = W1 + (size_t)p * 8192 * 256;
  unsigned short* dst = out + (size_t)blockIdx.z * 256 * 8192;
  const int f0 = blockIdx.x * 64, h0 = blockIdx.y * 64;
#pragma unroll
  for (int i = 0; i < 16; ++i) {
    int tt = i * 256 + threadIdx.x;
    int r = tt >> 6, c = tt & 63;
    t[r][c] = f2bf(src[(size_t)(f0 + r) * 256 + h0 + c]);
  }
  __syncthreads();
#pragma unroll
  for (int i = 0; i < 16; ++i) {
    int tt = i * 256 + threadIdx.x;
    int r = tt >> 6, c = tt & 63;
    dst[(size_t)(h0 + r) * 8192 + f0 + c] = t[c][r];
  }
}

// W2 f32 [p][256][128] -> bf16 transposed [p][128][256]
__global__ void k_cvt_w2(const float* __restrict__ W2, unsigned short* __restrict__ out) {
  const int p = blockIdx.x;
  const float* src = W2 + (size_t)p * 256 * 128;
  unsigned short* dst = out + (size_t)p * 128 * 256;
  for (int tt = threadIdx.x; tt < 128 * 256; tt += 256) {
    int j = tt >> 8, h = tt & 255;
    dst[tt] = f2bf(src[(size_t)h * 128 + j]);
  }
}

// ---------------- GEMM1: h1 = relu(features @ W1 + b1) ----------------
// 256x256 tile, BK=64, 8 waves (2Mx4N, per-wave 128x64 -> acc[8][4]).
// 2 LDS buffers (each A[256][64]+B[256][64] = 64 KiB), 4 phases per K-tile:
//  ph1: read A(mi0-3)+B(nj0-1) frags | stage A1(t+1) | BAR | 16 MFMA Q00 | BAR
//  ph2: read B(nj2-3)               | stage B0(t+1) | BAR | 16 MFMA Q01 | BAR
//  ph3: read A(mi4-7)               | stage B1(t+1) | BAR | 16 MFMA Q10 | BAR
//  ph4:                             | stage A0(t+2) | vmcnt(2) | BAR | 16 MFMA Q11 | BAR
// vmcnt(2) leaves only ph4's stage in flight -> tile t+1 fully landed.
// LDS swizzle: 16B-unit u of row r stored at phys unit u^(r&7); staged via
// pre-swizzled global source (rule 21); frag reads perfectly bank-balanced.
__global__ __launch_bounds__(512, 2) void k_gemm1(
    const unsigned short* __restrict__ A,    // [4096][8192] bf16
    const unsigned short* __restrict__ Bt,   // [z][256][8192] bf16
    const float* __restrict__ b1,
    unsigned short* __restrict__ h1,
    int p0) {
  __shared__ __align__(16) unsigned short S[65536];  // 128 KiB: [buf][A 16384 | B 16384]

  const int tid = threadIdx.x;
  const int lane = tid & 63;
  const int wave = tid >> 6;
  const int wm = wave >> 2;   // 0..1
  const int wn = wave & 3;    // 0..3

  // bijective chunked XCD swizzle
  const int nwg = gridDim.x * gridDim.y;
  const int orig = blockIdx.y * gridDim.x + blockIdx.x;
  const int q = nwg >> 3, r_ = nwg & 7;
  const int xcd = orig & 7, idx = orig >> 3;
  const int wg = (xcd < r_ ? xcd * (q + 1) : r_ * (q + 1) + (xcd - r_) * q) + idx;
  const int mx = wg & 15;     // gridDim.x == 16
  const int z = wg >> 4;
  const int p = p0 + z;
  const int m0 = mx * 256;

  const unsigned short* Ab = A + (size_t)m0 * 8192;
  const unsigned short* Bb = Bt + (size_t)z * 256 * 8192;

  // staging geometry: half = [128 rows][8 units of 16B]; thread t, round i:
  // element e = i*512+t; r = e>>3; phys unit = e&7; logical unit = (e&7)^(r&7)
  int e0 = tid, r0 = e0 >> 3, u0 = (e0 & 7) ^ (r0 & 7);
  int e1 = 512 + tid, r1e = e1 >> 3, u1 = (e1 & 7) ^ (r1e & 7);
  const size_t s0 = (size_t)r0 * 8192 + u0 * 8;
  const size_t s1 = (size_t)r1e * 8192 + u1 * 8;
  const int ld0 = (wave * 64) * 8;          // wave-uniform LDS short-offset, round 0
  const int ld1 = (512 + wave * 64) * 8;    // round 1

  auto stage = [&](int buf, int isB, int h, int T) {
    const unsigned short* gb = (isB ? Bb : Ab) + (size_t)h * 128 * 8192 + (size_t)T * 64;
    unsigned short* lb = S + buf * 32768 + isB * 16384 + h * 8192;
    gload16(gb + s0, lb + ld0);
    gload16(gb + s1, lb + ld1);
  };

  const int l15 = lane & 15, ks = lane >> 4;

  auto rdA = [&](int buf, int mi, int x) {
    int R = wm * 128 + mi * 16 + l15;
    int pu = (x * 4 + ks) ^ (R & 7);
    return __builtin_bit_cast(bf16x8, *(const short8_t*)(S + buf * 32768 + R * 64 + pu * 8));
  };
  auto rdB = [&](int buf, int nj, int x) {
    int R = wn * 64 + nj * 16 + l15;
    int pu = (x * 4 + ks) ^ (R & 7);
    return __builtin_bit_cast(bf16x8, *(const short8_t*)(S + buf * 32768 + 16384 + R * 64 + pu * 8));
  };

  f32x4 acc[8][4] = {};
  const int NT = 8192 / 64;  // 128 K-tiles

  auto kstep = [&](int t, int pf1, int pf4, int vm) {
    const int c = t & 1, nx = c ^ 1;
    bf16x8 aF[4][2], bL[2][2], bH[2][2];
    // ---- phase 1: Q00 ----
#pragma unroll
    for (int mi = 0; mi < 4; ++mi) { aF[mi][0] = rdA(c, mi, 0); aF[mi][1] = rdA(c, mi, 1); }
#pragma unroll
    for (int nj = 0; nj < 2; ++nj) { bL[nj][0] = rdB(c, nj, 0); bL[nj][1] = rdB(c, nj, 1); }
    if (pf1) stage(nx, 0, 1, t + 1);   // A-half1 of t+1
    BARRIER();
    __builtin_amdgcn_s_setprio(1);
#pragma unroll
    for (int mi = 0; mi < 4; ++mi)
#pragma unroll
      for (int nj = 0; nj < 2; ++nj) {
        acc[mi][nj] = __builtin_amdgcn_mfma_f32_16x16x32_bf16(aF[mi][0], bL[nj][0], acc[mi][nj], 0, 0, 0);
        acc[mi][nj] = __builtin_amdgcn_mfma_f32_16x16x32_bf16(aF[mi][1], bL[nj][1], acc[mi][nj], 0, 0, 0);
      }
    __builtin_amdgcn_s_setprio(0);
    BARRIER();
    // ---- phase 2: Q01 ----
#pragma unroll
    for (int nj = 0; nj < 2; ++nj) { bH[nj][0] = rdB(c, nj + 2, 0); bH[nj][1] = rdB(c, nj + 2, 1); }
    if (pf1) stage(nx, 1, 0, t + 1);   // B-half0 of t+1
    BARRIER();
    __builtin_amdgcn_s_setprio(1);
#pragma unroll
    for (int mi = 0; mi < 4; ++mi)
#pragma unroll
      for (int nj = 0; nj < 2; ++nj) {
        acc[mi][nj + 2] = __builtin_amdgcn_mfma_f32_16x16x32_bf16(aF[mi][0], bH[nj][0], acc[mi][nj + 2], 0, 0, 0);
        acc[mi][nj + 2] = __builtin_amdgcn_mfma_f32_16x16x32_bf16(aF[mi][1], bH[nj][1], acc[mi][nj + 2], 0, 0, 0);
      }
    __builtin_amdgcn_s_setprio(0);
    BARRIER();
    // ---- phase 3: Q10 ----
#pragma unroll
    for (int mi = 0; mi < 4; ++mi) { aF[mi][0] = rdA(c, mi + 4, 0); aF[mi][1] = rdA(c, mi + 4, 1); }
    if (pf1) stage(nx, 1, 1, t + 1);   // B-half1 of t+1
    BARRIER();
    __builtin_amdgcn_s_setprio(1);
#pragma unroll
    for (int mi = 0; mi < 4; ++mi)
#pragma unroll
      for (int nj = 0; nj < 2; ++nj) {
        acc[mi + 4][nj] = __builtin_amdgcn_mfma_f32_16x16x32_bf16(aF[mi][0], bL[nj][0], acc[mi + 4][nj], 0, 0, 0);
        acc[mi + 4][nj] = __builtin_amdgcn_mfma_f32_16x16x32_bf16(aF[mi][1], bL[nj][1], acc[mi + 4][nj], 0, 0, 0);
      }
    __builtin_amdgcn_s_setprio(0);
    BARRIER();
    // ---- phase 4: Q11 ----
    if (pf4) stage(c, 0, 0, t + 2);    // A-half0 of t+2 (buffer c's reads are done)
    if (vm == 2)      asm volatile("s_waitcnt vmcnt(2)" ::: "memory");
    else if (vm == 0) asm volatile("s_waitcnt vmcnt(0)" ::: "memory");
    BARRIER();
    __builtin_amdgcn_s_setprio(1);
#pragma unroll
    for (int mi = 0; mi < 4; ++mi)
#pragma unroll
      for (int nj = 0; nj < 2; ++nj) {
        acc[mi + 4][nj + 2] = __builtin_amdgcn_mfma_f32_16x16x32_bf16(aF[mi][0], bH[nj][0], acc[mi + 4][nj + 2], 0, 0, 0);
        acc[mi + 4][nj + 2] = __builtin_amdgcn_mfma_f32_16x16x32_bf16(aF[mi][1], bH[nj][1], acc[mi + 4][nj + 2], 0, 0, 0);
      }
    __builtin_amdgcn_s_setprio(0);
    BARRIER();
  };

  // prologue: tile0 all 4 halves into buf0, A-half0 of tile1 into buf1
  stage(0, 0, 0, 0); stage(0, 0, 1, 0); stage(0, 1, 0, 0); stage(0, 1, 1, 0);
  stage(1, 0, 0, 1);
  asm volatile("s_waitcnt vmcnt(2)" ::: "memory");
  BARRIER();

  for (int t = 0; t < NT - 2; ++t) kstep(t, 1, 1, 2);
  kstep(NT - 2, 1, 0, 0);
  kstep(NT - 1, 0, 0, -1);

  // epilogue: + b1, relu, h1 bf16 [p][4096][256]
  const int rg = lane >> 4;
#pragma unroll
  for (int nj = 0; nj < 4; ++nj) {
    const int col = wn * 64 + nj * 16 + l15;
    const float bb = b1[p * 256 + col];
#pragma unroll
    for (int mi = 0; mi < 8; ++mi) {
      const int rbase = m0 + wm * 128 + mi * 16 + rg * 4;
#pragma unroll
      for (int rr = 0; rr < 4; ++rr) {
        float v = acc[mi][nj][rr] + bb;
        v = v > 0.f ? v : 0.f;
        h1[((size_t)p * 4096 + rbase + rr) * 256 + col] = f2bf(v);
      }
    }
  }
}

// ---------------- GEMM2+3 fused ----------------
__global__ __launch_bounds__(256, 2) void k_gemm23(
    const unsigned short* __restrict__ h1,   // [29][4096][256] bf16
    const unsigned short* __restrict__ W2t,  // [29][128][256] bf16
    const float* __restrict__ b2,
    const float* __restrict__ W3,
    const float* __restrict__ b3,
    float* __restrict__ out) {               // [4096][29]
  __shared__ __align__(16) unsigned short lds_a[128 * 64];
  __shared__ __align__(16) unsigned short lds_b[128 * 64];
  const int tid = threadIdx.x;
  const int lane = tid & 63;
  const int wave = tid >> 6;
  const int m0 = blockIdx.x * 128;
  const int p = blockIdx.y;

  const unsigned short* Ab = h1 + ((size_t)p * 4096 + m0) * 256;
  const unsigned short* Bb = W2t + (size_t)p * 128 * 256;

  f32x4 acc[2][8] = {};

  for (int k0 = 0; k0 < 256; k0 += 64) {
    __syncthreads();
#pragma unroll
    for (int i = 0; i < 4; ++i) {
      int t = i * 256 + tid;
      int r = t >> 3;
      int uu = (t & 7) ^ (r & 7);
      gload16(Ab + (size_t)r * 256 + k0 + uu * 8, &lds_a[(i * 256 + wave * 64) * 8]);
      gload16(Bb + (size_t)r * 256 + k0 + uu * 8, &lds_b[(i * 256 + wave * 64) * 8]);
    }
    __syncthreads();
#pragma unroll
    for (int kk = 0; kk < 64; kk += 32) {
      const int ku = (kk >> 3) + (lane >> 4);
      bf16x8 af[2], bfv[8];
#pragma unroll
      for (int mi = 0; mi < 2; ++mi) {
        int row = wave * 32 + mi * 16 + (lane & 15);
        int u = ku ^ (row & 7);
        af[mi] = __builtin_bit_cast(bf16x8, *(const short8_t*)&lds_a[row * 64 + u * 8]);
      }
#pragma unroll
      for (int nj = 0; nj < 8; ++nj) {
        int row = nj * 16 + (lane & 15);
        int u = ku ^ (row & 7);
        bfv[nj] = __builtin_bit_cast(bf16x8, *(const short8_t*)&lds_b[row * 64 + u * 8]);
      }
#pragma unroll
      for (int mi = 0; mi < 2; ++mi)
#pragma unroll
        for (int nj = 0; nj < 8; ++nj)
          acc[mi][nj] = __builtin_amdgcn_mfma_f32_16x16x32_bf16(af[mi], bfv[nj], acc[mi][nj], 0, 0, 0);
    }
  }

  float b2v[8], w3v[8];
  const int c16 = lane & 15;
#pragma unroll
  for (int nj = 0; nj < 8; ++nj) {
    int c = nj * 16 + c16;
    b2v[nj] = b2[p * 128 + c];
    w3v[nj] = W3[p * 128 + c];
  }
  const float b3p = b3[p];
#pragma unroll
  for (int mi = 0; mi < 2; ++mi) {
#pragma unroll
    for (int r = 0; r < 4; ++r) {
      float s = 0.f;
#pragma unroll
      for (int nj = 0; nj < 8; ++nj) {
        float v = acc[mi][nj][r] + b2v[nj];
        v = v > 0.f ? v : 0.f;
        s += v * w3v[nj];
      }
      s += __shfl_xor(s, 1);
      s += __shfl_xor(s, 2);
      s += __shfl_xor(s, 4);
      s += __shfl_xor(s, 8);
      if ((lane & 15) == 0) {
        int m = m0 + wave * 32 + mi * 16 + (lane >> 4) * 4 + r;
        float logit = s + b3p;
        out[(size_t)m * 29 + p] = 1.f / (1.f + __expf(-logit));
      }
    }
  }
}

// ---------------- launch ----------------
extern "C" void kernel_launch(void* const* d_in, const int* in_sizes, int n_in,
                              void* d_out, int out_size, void* d_ws, size_t ws_size,
                              hipStream_t stream) {
  const float* features = (const float*)d_in[0];
  const float* W1 = (const float*)d_in[1];
  const float* b1 = (const float*)d_in[2];
  const float* W2 = (const float*)d_in[3];
  const float* b2 = (const float*)d_in[4];
  const float* W3 = (const float*)d_in[5];
  const float* b3 = (const float*)d_in[6];
  float* out = (float*)d_out;

  char* ws = (char*)d_ws;
  const size_t featB = (size_t)4096 * 8192 * 2;       // 64 MB
  const size_t h1B   = (size_t)29 * 4096 * 256 * 2;   // 58 MB
  const size_t w2B   = (size_t)29 * 128 * 256 * 2;    // 1.9 MB
  const size_t w1pp  = (size_t)256 * 8192 * 2;        // 4 MB per predicate

  unsigned short* featbf = (unsigned short*)ws;
  unsigned short* h1bf   = (unsigned short*)(ws + featB);
  unsigned short* w2t    = (unsigned short*)(ws + featB + h1B);
  unsigned short* w1t    = (unsigned short*)(ws + featB + h1B + w2B);

  size_t base = featB + h1B + w2B;
  size_t rem = (ws_size > base) ? (ws_size - base) : 0;
  int CH = (int)(rem / w1pp);
  if (CH > 29) CH = 29;
  if (CH < 1) CH = 1;

  k_cvt_feat<<<2048, 256, 0, stream>>>(features, featbf);
  k_cvt_w2<<<29, 256, 0, stream>>>(W2, w2t);

  for (int p0 = 0; p0 < 29; p0 += CH) {
    int c = (29 - p0) < CH ? (29 - p0) : CH;
    k_cvt_w1<<<dim3(128, 4, c), 256, 0, stream>>>(W1, w1t, p0);
    k_gemm1<<<dim3(16, c), 512, 0, stream>>>(featbf, w1t, b1, h1bf, p0);
  }

  k_gemm23<<<dim3(32, 29), 256, 0, stream>>>(h1bf, w2t, b2, W3, b3, out);
}

// Round 4
// 563.195 us; speedup vs baseline: 1.5135x; 1.0904x over previous
//
#include <hip/hip_runtime.h>
#include <hip/hip_bf16.h>

typedef __attribute__((ext_vector_type(8))) short short8_t;
typedef __attribute__((ext_vector_type(8))) __bf16 bf16x8;
typedef __attribute__((ext_vector_type(4))) float f32x4;

__device__ __forceinline__ void gload16(const void* g, void* l) {
  __builtin_amdgcn_global_load_lds(
      (const __attribute__((address_space(1))) void*)g,
      (__attribute__((address_space(3))) void*)l, 16, 0, 0);
}

__device__ __forceinline__ unsigned short f2bf(float f) {
  __hip_bfloat16 h = __float2bfloat16(f);
  return __builtin_bit_cast(unsigned short, h);
}

#define BARRIER() asm volatile("s_barrier" ::: "memory")

// ---------------- conversion kernels ----------------

__global__ void k_cvt_feat(const float* __restrict__ in, unsigned short* __restrict__ out) {
  const size_t N = (size_t)4096 * 8192;
  size_t i = ((size_t)blockIdx.x * 256 + threadIdx.x) * 4;
  const size_t stride = (size_t)gridDim.x * 256 * 4;
  for (; i < N; i += stride) {
    float4 v = *(const float4*)(in + i);
    ushort4 o;
    o.x = f2bf(v.x); o.y = f2bf(v.y); o.z = f2bf(v.z); o.w = f2bf(v.w);
    *(ushort4*)(out + i) = o;
  }
}

// W1 f32 [p][8192][256] -> bf16 transposed chunk-local [z][256][8192]
__global__ void k_cvt_w1(const float* __restrict__ W1, unsigned short* __restrict__ out, int p0) {
  __shared__ unsigned short t[64][66];
  const int p = p0 + blockIdx.z;
  const float* src = W1 + (size_t)p * 8192 * 256;
  unsigned short* dst = out + (size_t)blockIdx.z * 256 * 8192;
  const int f0 = blockIdx.x * 64, h0 = blockIdx.y * 64;
#pragma unroll
  for (int i = 0; i < 16; ++i) {
    int tt = i * 256 + threadIdx.x;
    int r = tt >> 6, c = tt & 63;
    t[r][c] = f2bf(src[(size_t)(f0 + r) * 256 + h0 + c]);
  }
  __syncthreads();
#pragma unroll
  for (int i = 0; i < 16; ++i) {
    int tt = i * 256 + threadIdx.x;
    int r = tt >> 6, c = tt & 63;
    dst[(size_t)(h0 + r) * 8192 + f0 + c] = t[c][r];
  }
}

// W2 f32 [p][256][128] -> bf16 transposed [p][128][256]
__global__ void k_cvt_w2(const float* __restrict__ W2, unsigned short* __restrict__ out) {
  const int p = blockIdx.x;
  const float* src = W2 + (size_t)p * 256 * 128;
  unsigned short* dst = out + (size_t)p * 128 * 256;
  for (int tt = threadIdx.x; tt < 128 * 256; tt += 256) {
    int j = tt >> 8, h = tt & 255;
    dst[tt] = f2bf(src[(size_t)h * 128 + j]);
  }
}

// ---------------- GEMM1: h1 = relu(features @ W1 + b1) ----------------
// 256x256 tile, BK=64, 8 waves. Per PHASE all 8 waves compute ONE 128x128
// C-quadrant (wave w -> 64x32 sub-block: rows (w>>2)*64, cols (w&3)*32).
//  ph1: read A-half0(8 b128)+B-half0(4) | stage A0,B0(t+1) | BAR | MFMA Q00 | vmcnt(4) | BAR
//  ph2: read B-half1(4)                |                  | BAR | MFMA Q01 (A regs reused) | BAR
//  ph3: read A-half1(8)                | stage B1,A1(t+1) | BAR | MFMA Q10 (B0 regs reused)| BAR
//  ph4: (no reads)                     |                  |       MFMA Q11 | vmcnt(4) | BAR
// Wait accounting (loads; 2 gload/half): start-of-tile outstanding = {B1(t),A1(t)}=4.
//  ph1 +4 -> 8; vmcnt(4) retires B1(t),A1(t) (needed ph2/ph3, issued t-1.ph3: 2-3 phase slack).
//  ph3 +4 -> 8; ph4 vmcnt(4) retires A0,B0(t+1) (needed t+1.ph1, issued t.ph1: 3 phase slack).
// LDS: 2 buf x (A 32K + B 32K) = 128 KiB; halves [128][8 units of 16B],
// unit u of row r at phys u^(r&7) via pre-swizzled global source (rule 21).
__global__ __launch_bounds__(512, 2) void k_gemm1(
    const unsigned short* __restrict__ A,    // [4096][8192] bf16
    const unsigned short* __restrict__ Bt,   // [z][256][8192] bf16
    const float* __restrict__ b1,
    unsigned short* __restrict__ h1,
    int p0) {
  __shared__ __align__(16) unsigned short S[65536];  // 128 KiB

  const int tid = threadIdx.x;
  const int lane = tid & 63;
  const int wave = tid >> 6;
  const int sr = (wave >> 2) * 64;   // sub-row within 128-row half
  const int sc = (wave & 3) * 32;    // sub-col within 128-col half

  // bijective chunked XCD swizzle; decode mx-major so one XCD shares A panels
  const int nz = gridDim.y;
  const int nwg = gridDim.x * nz;
  const int orig = blockIdx.y * gridDim.x + blockIdx.x;
  const int q = nwg >> 3, r_ = nwg & 7;
  const int xcd = orig & 7, idx = orig >> 3;
  const int wg = (xcd < r_ ? xcd * (q + 1) : r_ * (q + 1) + (xcd - r_) * q) + idx;
  const int mx = wg / nz;
  const int z = wg % nz;
  const int p = p0 + z;
  const int m0 = mx * 256;

  const unsigned short* Ab = A + (size_t)m0 * 8192;
  const unsigned short* Bb = Bt + (size_t)z * 256 * 8192;

  // staging: half = [128 rows][8 units]; thread t round i: e=i*512+t;
  // r=e>>3 (half-local), phys unit=e&7, global unit=(e&7)^(r&7)
  int e0 = tid, r0 = e0 >> 3, u0 = (e0 & 7) ^ (r0 & 7);
  int e1 = 512 + tid, r1e = e1 >> 3, u1 = (e1 & 7) ^ (r1e & 7);
  const size_t s0 = (size_t)r0 * 8192 + u0 * 8;
  const size_t s1 = (size_t)r1e * 8192 + u1 * 8;
  const int ld0 = (wave * 64) * 8;
  const int ld1 = (512 + wave * 64) * 8;

  auto stage = [&](int buf, int isB, int h, int T) {
    const unsigned short* gb = (isB ? Bb : Ab) + (size_t)h * 128 * 8192 + (size_t)T * 64;
    unsigned short* lb = S + buf * 32768 + isB * 16384 + h * 8192;
    gload16(gb + s0, lb + ld0);
    gload16(gb + s1, lb + ld1);
  };

  const int l15 = lane & 15, ks = lane >> 4;

  auto rdA = [&](int buf, int h, int mi, int x) {
    int R = sr + mi * 16 + l15;
    int pu = (x * 4 + ks) ^ (R & 7);
    return __builtin_bit_cast(bf16x8, *(const short8_t*)(S + buf * 32768 + h * 8192 + R * 64 + pu * 8));
  };
  auto rdB = [&](int buf, int v, int nj, int x) {
    int R = sc + nj * 16 + l15;
    int pu = (x * 4 + ks) ^ (R & 7);
    return __builtin_bit_cast(bf16x8, *(const short8_t*)(S + buf * 32768 + 16384 + v * 8192 + R * 64 + pu * 8));
  };

  f32x4 acc[4][4][2] = {};   // [quadrant q=h*2+v][mi][nj]
  const int NT = 8192 / 64;  // 128 K-tiles

  auto kstep = [&](int t, int pf, int vm1, int vm4) {
    const int c = t & 1, nx = c ^ 1;
    bf16x8 a[4][2], bl[2][2], bh[2][2];
    // ---- ph1: Q00 ----
#pragma unroll
    for (int mi = 0; mi < 4; ++mi) { a[mi][0] = rdA(c, 0, mi, 0); a[mi][1] = rdA(c, 0, mi, 1); }
#pragma unroll
    for (int nj = 0; nj < 2; ++nj) { bl[nj][0] = rdB(c, 0, nj, 0); bl[nj][1] = rdB(c, 0, nj, 1); }
    if (pf) { stage(nx, 0, 0, t + 1); stage(nx, 1, 0, t + 1); }
    BARRIER();
    __builtin_amdgcn_s_setprio(1);
#pragma unroll
    for (int mi = 0; mi < 4; ++mi)
#pragma unroll
      for (int nj = 0; nj < 2; ++nj) {
        acc[0][mi][nj] = __builtin_amdgcn_mfma_f32_16x16x32_bf16(a[mi][0], bl[nj][0], acc[0][mi][nj], 0, 0, 0);
        acc[0][mi][nj] = __builtin_amdgcn_mfma_f32_16x16x32_bf16(a[mi][1], bl[nj][1], acc[0][mi][nj], 0, 0, 0);
      }
    __builtin_amdgcn_s_setprio(0);
    if (vm1 == 4)      asm volatile("s_waitcnt vmcnt(4)" ::: "memory");
    else if (vm1 == 0) asm volatile("s_waitcnt vmcnt(0)" ::: "memory");
    BARRIER();
    // ---- ph2: Q01 (reuse a) ----
#pragma unroll
    for (int nj = 0; nj < 2; ++nj) { bh[nj][0] = rdB(c, 1, nj, 0); bh[nj][1] = rdB(c, 1, nj, 1); }
    BARRIER();
    __builtin_amdgcn_s_setprio(1);
#pragma unroll
    for (int mi = 0; mi < 4; ++mi)
#pragma unroll
      for (int nj = 0; nj < 2; ++nj) {
        acc[1][mi][nj] = __builtin_amdgcn_mfma_f32_16x16x32_bf16(a[mi][0], bh[nj][0], acc[1][mi][nj], 0, 0, 0);
        acc[1][mi][nj] = __builtin_amdgcn_mfma_f32_16x16x32_bf16(a[mi][1], bh[nj][1], acc[1][mi][nj], 0, 0, 0);
      }
    __builtin_amdgcn_s_setprio(0);
    BARRIER();
    // ---- ph3: Q10 (reuse bl) ----
#pragma unroll
    for (int mi = 0; mi < 4; ++mi) { a[mi][0] = rdA(c, 1, mi, 0); a[mi][1] = rdA(c, 1, mi, 1); }
    if (pf) { stage(nx, 1, 1, t + 1); stage(nx, 0, 1, t + 1); }
    BARRIER();
    __builtin_amdgcn_s_setprio(1);
#pragma unroll
    for (int mi = 0; mi < 4; ++mi)
#pragma unroll
      for (int nj = 0; nj < 2; ++nj) {
        acc[2][mi][nj] = __builtin_amdgcn_mfma_f32_16x16x32_bf16(a[mi][0], bl[nj][0], acc[2][mi][nj], 0, 0, 0);
        acc[2][mi][nj] = __builtin_amdgcn_mfma_f32_16x16x32_bf16(a[mi][1], bl[nj][1], acc[2][mi][nj], 0, 0, 0);
      }
    __builtin_amdgcn_s_setprio(0);
    BARRIER();
    // ---- ph4: Q11 (reuse a, bh; no LDS reads) ----
    __builtin_amdgcn_s_setprio(1);
#pragma unroll
    for (int mi = 0; mi < 4; ++mi)
#pragma unroll
      for (int nj = 0; nj < 2; ++nj) {
        acc[3][mi][nj] = __builtin_amdgcn_mfma_f32_16x16x32_bf16(a[mi][0], bh[nj][0], acc[3][mi][nj], 0, 0, 0);
        acc[3][mi][nj] = __builtin_amdgcn_mfma_f32_16x16x32_bf16(a[mi][1], bh[nj][1], acc[3][mi][nj], 0, 0, 0);
      }
    __builtin_amdgcn_s_setprio(0);
    if (vm4 == 4)      asm volatile("s_waitcnt vmcnt(4)" ::: "memory");
    else if (vm4 == 0) asm volatile("s_waitcnt vmcnt(0)" ::: "memory");
    BARRIER();
  };

  // prologue: tile0 halves in order A0,B0 then B1,A1; retire A0,B0
  stage(0, 0, 0, 0); stage(0, 1, 0, 0);
  stage(0, 1, 1, 0); stage(0, 0, 1, 0);
  asm volatile("s_waitcnt vmcnt(4)" ::: "memory");
  BARRIER();

  for (int t = 0; t < NT - 1; ++t) kstep(t, 1, 4, 4);
  kstep(NT - 1, 0, 0, -1);

  // epilogue: + b1, relu, h1 bf16 [p][4096][256]
  const int rg = lane >> 4;
#pragma unroll
  for (int qh = 0; qh < 2; ++qh)
#pragma unroll
    for (int qv = 0; qv < 2; ++qv) {
      const int qq = qh * 2 + qv;
#pragma unroll
      for (int nj = 0; nj < 2; ++nj) {
        const int col = qv * 128 + sc + nj * 16 + l15;
        const float bb = b1[p * 256 + col];
#pragma unroll
        for (int mi = 0; mi < 4; ++mi) {
          const int rbase = m0 + qh * 128 + sr + mi * 16 + rg * 4;
#pragma unroll
          for (int rr = 0; rr < 4; ++rr) {
            float v = acc[qq][mi][nj][rr] + bb;
            v = v > 0.f ? v : 0.f;
            h1[((size_t)p * 4096 + rbase + rr) * 256 + col] = f2bf(v);
          }
        }
      }
    }
}

// ---------------- GEMM2+3 fused ----------------
__global__ __launch_bounds__(256, 2) void k_gemm23(
    const unsigned short* __restrict__ h1,   // [29][4096][256] bf16
    const unsigned short* __restrict__ W2t,  // [29][128][256] bf16
    const float* __restrict__ b2,
    const float* __restrict__ W3,
    const float* __restrict__ b3,
    float* __restrict__ out) {               // [4096][29]
  __shared__ __align__(16) unsigned short lds_a[128 * 64];
  __shared__ __align__(16) unsigned short lds_b[128 * 64];
  const int tid = threadIdx.x;
  const int lane = tid & 63;
  const int wave = tid >> 6;
  const int m0 = blockIdx.x * 128;
  const int p = blockIdx.y;

  const unsigned short* Ab = h1 + ((size_t)p * 4096 + m0) * 256;
  const unsigned short* Bb = W2t + (size_t)p * 128 * 256;

  f32x4 acc[2][8] = {};

  for (int k0 = 0; k0 < 256; k0 += 64) {
    __syncthreads();
#pragma unroll
    for (int i = 0; i < 4; ++i) {
      int t = i * 256 + tid;
      int r = t >> 3;
      int uu = (t & 7) ^ (r & 7);
      gload16(Ab + (size_t)r * 256 + k0 + uu * 8, &lds_a[(i * 256 + wave * 64) * 8]);
      gload16(Bb + (size_t)r * 256 + k0 + uu * 8, &lds_b[(i * 256 + wave * 64) * 8]);
    }
    __syncthreads();
#pragma unroll
    for (int kk = 0; kk < 64; kk += 32) {
      const int ku = (kk >> 3) + (lane >> 4);
      bf16x8 af[2], bfv[8];
#pragma unroll
      for (int mi = 0; mi < 2; ++mi) {
        int row = wave * 32 + mi * 16 + (lane & 15);
        int u = ku ^ (row & 7);
        af[mi] = __builtin_bit_cast(bf16x8, *(const short8_t*)&lds_a[row * 64 + u * 8]);
      }
#pragma unroll
      for (int nj = 0; nj < 8; ++nj) {
        int row = nj * 16 + (lane & 15);
        int u = ku ^ (row & 7);
        bfv[nj] = __builtin_bit_cast(bf16x8, *(const short8_t*)&lds_b[row * 64 + u * 8]);
      }
#pragma unroll
      for (int mi = 0; mi < 2; ++mi)
#pragma unroll
        for (int nj = 0; nj < 8; ++nj)
          acc[mi][nj] = __builtin_amdgcn_mfma_f32_16x16x32_bf16(af[mi], bfv[nj], acc[mi][nj], 0, 0, 0);
    }
  }

  float b2v[8], w3v[8];
  const int c16 = lane & 15;
#pragma unroll
  for (int nj = 0; nj < 8; ++nj) {
    int c = nj * 16 + c16;
    b2v[nj] = b2[p * 128 + c];
    w3v[nj] = W3[p * 128 + c];
  }
  const float b3p = b3[p];
#pragma unroll
  for (int mi = 0; mi < 2; ++mi) {
#pragma unroll
    for (int r = 0; r < 4; ++r) {
      float s = 0.f;
#pragma unroll
      for (int nj = 0; nj < 8; ++nj) {
        float v = acc[mi][nj][r] + b2v[nj];
        v = v > 0.f ? v : 0.f;
        s += v * w3v[nj];
      }
      s += __shfl_xor(s, 1);
      s += __shfl_xor(s, 2);
      s += __shfl_xor(s, 4);
      s += __shfl_xor(s, 8);
      if ((lane & 15) == 0) {
        int m = m0 + wave * 32 + mi * 16 + (lane >> 4) * 4 + r;
        float logit = s + b3p;
        out[(size_t)m * 29 + p] = 1.f / (1.f + __expf(-logit));
      }
    }
  }
}

// ---------------- launch ----------------
extern "C" void kernel_launch(void* const* d_in, const int* in_sizes, int n_in,
                              void* d_out, int out_size, void* d_ws, size_t ws_size,
                              hipStream_t stream) {
  const float* features = (const float*)d_in[0];
  const float* W1 = (const float*)d_in[1];
  const float* b1 = (const float*)d_in[2];
  const float* W2 = (const float*)d_in[3];
  const float* b2 = (const float*)d_in[4];
  const float* W3 = (const float*)d_in[5];
  const float* b3 = (const float*)d_in[6];
  float* out = (float*)d_out;

  char* ws = (char*)d_ws;
  const size_t featB = (size_t)4096 * 8192 * 2;       // 64 MB
  const size_t h1B   = (size_t)29 * 4096 * 256 * 2;   // 58 MB
  const size_t w2B   = (size_t)29 * 128 * 256 * 2;    // 1.9 MB
  const size_t w1pp  = (size_t)256 * 8192 * 2;        // 4 MB per predicate

  unsigned short* featbf = (unsigned short*)ws;
  unsigned short* h1bf   = (unsigned short*)(ws + featB);
  unsigned short* w2t    = (unsigned short*)(ws + featB + h1B);
  unsigned short* w1t    = (unsigned short*)(ws + featB + h1B + w2B);

  size_t base = featB + h1B + w2B;
  size_t rem = (ws_size > base) ? (ws_size - base) : 0;
  int CH = (int)(rem / w1pp);
  if (CH > 29) CH = 29;
  if (CH < 1) CH = 1;

  k_cvt_feat<<<2048, 256, 0, stream>>>(features, featbf);
  k_cvt_w2<<<29, 256, 0, stream>>>(W2, w2t);

  for (int p0 = 0; p0 < 29; p0 += CH) {
    int c = (29 - p0) < CH ? (29 - p0) : CH;
    k_cvt_w1<<<dim3(128, 4, c), 256, 0, stream>>>(W1, w1t, p0);
    k_gemm1<<<dim3(16, c), 512, 0, stream>>>(featbf, w1t, b1, h1bf, p0);
  }

  k_gemm23<<<dim3(32, 29), 256, 0, stream>>>(h1bf, w2t, b2, W3, b3, out);
}

// Round 5
// 548.338 us; speedup vs baseline: 1.5546x; 1.0271x over previous
//
#include <hip/hip_runtime.h>
#include <hip/hip_bf16.h>

typedef __attribute__((ext_vector_type(8))) short short8_t;
typedef __attribute__((ext_vector_type(8))) __bf16 bf16x8;
typedef __attribute__((ext_vector_type(4))) float f32x4;

__device__ __forceinline__ void gload16(const void* g, void* l) {
  __builtin_amdgcn_global_load_lds(
      (const __attribute__((address_space(1))) void*)g,
      (__attribute__((address_space(3))) void*)l, 16, 0, 0);
}

__device__ __forceinline__ unsigned short f2bf(float f) {
  __hip_bfloat16 h = __float2bfloat16(f);
  return __builtin_bit_cast(unsigned short, h);
}

#define BARRIER() asm volatile("s_barrier" ::: "memory")

// ---------------- conversion kernels ----------------

__global__ void k_cvt_feat(const float* __restrict__ in, unsigned short* __restrict__ out) {
  const size_t N = (size_t)4096 * 8192;
  size_t i = ((size_t)blockIdx.x * 256 + threadIdx.x) * 4;
  const size_t stride = (size_t)gridDim.x * 256 * 4;
  for (; i < N; i += stride) {
    float4 v = *(const float4*)(in + i);
    ushort4 o;
    o.x = f2bf(v.x); o.y = f2bf(v.y); o.z = f2bf(v.z); o.w = f2bf(v.w);
    *(ushort4*)(out + i) = o;
  }
}

// W1 f32 [p][8192][256] -> bf16 transposed chunk-local [z][256][8192]
__global__ void k_cvt_w1(const float* __restrict__ W1, unsigned short* __restrict__ out, int p0) {
  __shared__ unsigned short t[64][66];
  const int p = p0 + blockIdx.z;
  const float* src = W1 + (size_t)p * 8192 * 256;
  unsigned short* dst = out + (size_t)blockIdx.z * 256 * 8192;
  const int f0 = blockIdx.x * 64, h0 = blockIdx.y * 64;
#pragma unroll
  for (int i = 0; i < 16; ++i) {
    int tt = i * 256 + threadIdx.x;
    int r = tt >> 6, c = tt & 63;
    t[r][c] = f2bf(src[(size_t)(f0 + r) * 256 + h0 + c]);
  }
  __syncthreads();
#pragma unroll
  for (int i = 0; i < 16; ++i) {
    int tt = i * 256 + threadIdx.x;
    int r = tt >> 6, c = tt & 63;
    dst[(size_t)(h0 + r) * 8192 + f0 + c] = t[c][r];
  }
}

// W2 f32 [p][256][128] -> bf16 transposed [p][128][256]
__global__ void k_cvt_w2(const float* __restrict__ W2, unsigned short* __restrict__ out) {
  const int p = blockIdx.x;
  const float* src = W2 + (size_t)p * 256 * 128;
  unsigned short* dst = out + (size_t)p * 128 * 256;
  for (int tt = threadIdx.x; tt < 128 * 256; tt += 256) {
    int j = tt >> 8, h = tt & 255;
    dst[tt] = f2bf(src[(size_t)h * 128 + j]);
  }
}

// ---------------- GEMM1: h1 = relu(features @ W1 + b1) ----------------
// 256x256 tile, BK=64, 8 waves; per phase all 8 waves compute ONE C-quadrant
// (wave w -> rows (w>>2)*64, cols (w&3)*32 of the quadrant).
// Depth-2 tile prefetch: during tile t, stage tile t+2 into buffer t&1's
// slots as they free:
//  ph1: read A0(8 b128)+B0lo(4)                  | BAR | MFMA Q00 | BAR
//  ph2: read B1(4)       | stage A0(t+2)         | BAR | MFMA Q01 | BAR
//  ph3: read A1(8)       | stage B1(t+2)         | BAR | MFMA Q10 | BAR
//  ph4:                  | stage B0(t+2),A1(t+2) | MFMA Q11 | vmcnt(8) | BAR
// Slot-free proof: A0(t) readers done at end-ph1 barrier -> stage at ph2 OK;
// B1(t) done end-ph2 -> ph3 OK; B0(t),A1(t) done end-ph3 -> ph4 OK.
// vmcnt(8) at end-ph4(t) retires tile t+1's 8 loads (youngest issued ph4(t-1),
// 4 phases earlier ~1000+cy >= HBM latency); leaves t+2's 8 in flight.
// LDS: 2 buf x (A 32K + B 32K) = 128 KiB; halves [128][8 units of 16B],
// unit u of row r at phys u^(r&7) via pre-swizzled global source.
__global__ __launch_bounds__(512, 2) void k_gemm1(
    const unsigned short* __restrict__ A,    // [4096][8192] bf16
    const unsigned short* __restrict__ Bt,   // [z][256][8192] bf16
    const float* __restrict__ b1,
    unsigned short* __restrict__ h1,
    int p0) {
  __shared__ __align__(16) unsigned short S[65536];  // 128 KiB

  const int tid = threadIdx.x;
  const int lane = tid & 63;
  const int wave = tid >> 6;
  const int sr = (wave >> 2) * 64;
  const int sc = (wave & 3) * 32;

  // bijective chunked XCD swizzle; z-MAJOR decode: 16 consecutive wgs on one
  // XCD share predicate z -> B panel (4MB) resident in that XCD's L2.
  const int nwg = gridDim.x * gridDim.y;
  const int orig = blockIdx.y * gridDim.x + blockIdx.x;
  const int q = nwg >> 3, r_ = nwg & 7;
  const int xcd = orig & 7, idx = orig >> 3;
  const int wg = (xcd < r_ ? xcd * (q + 1) : r_ * (q + 1) + (xcd - r_) * q) + idx;
  const int mx = wg & 15;     // gridDim.x == 16
  const int z = wg >> 4;
  const int p = p0 + z;
  const int m0 = mx * 256;

  const unsigned short* Ab = A + (size_t)m0 * 8192;
  const unsigned short* Bb = Bt + (size_t)z * 256 * 8192;

  // staging: half = [128 rows][8 units]; thread t round i: e=i*512+t;
  // r=e>>3, phys unit=e&7, global unit=(e&7)^(r&7)
  int e0 = tid, r0 = e0 >> 3, u0 = (e0 & 7) ^ (r0 & 7);
  int e1 = 512 + tid, r1e = e1 >> 3, u1 = (e1 & 7) ^ (r1e & 7);
  const size_t s0 = (size_t)r0 * 8192 + u0 * 8;
  const size_t s1 = (size_t)r1e * 8192 + u1 * 8;
  const int ld0 = (wave * 64) * 8;
  const int ld1 = (512 + wave * 64) * 8;

  auto stage = [&](int buf, int isB, int h, int T) {
    const unsigned short* gb = (isB ? Bb : Ab) + (size_t)h * 128 * 8192 + (size_t)T * 64;
    unsigned short* lb = S + buf * 32768 + isB * 16384 + h * 8192;
    gload16(gb + s0, lb + ld0);
    gload16(gb + s1, lb + ld1);
  };

  const int l15 = lane & 15, ks = lane >> 4;

  auto rdA = [&](int buf, int h, int mi, int x) {
    int R = sr + mi * 16 + l15;
    int pu = (x * 4 + ks) ^ (R & 7);
    return __builtin_bit_cast(bf16x8, *(const short8_t*)(S + buf * 32768 + h * 8192 + R * 64 + pu * 8));
  };
  auto rdB = [&](int buf, int v, int nj, int x) {
    int R = sc + nj * 16 + l15;
    int pu = (x * 4 + ks) ^ (R & 7);
    return __builtin_bit_cast(bf16x8, *(const short8_t*)(S + buf * 32768 + 16384 + v * 8192 + R * 64 + pu * 8));
  };

  f32x4 acc[4][4][2] = {};   // [quadrant][mi][nj]
  const int NT = 8192 / 64;  // 128 K-tiles

  auto kstep = [&](int t, int pf, int vm) {
    const int c = t & 1;
    bf16x8 a[4][2], bl[2][2], bh[2][2];
    // ---- ph1: Q00 ----
#pragma unroll
    for (int mi = 0; mi < 4; ++mi) { a[mi][0] = rdA(c, 0, mi, 0); a[mi][1] = rdA(c, 0, mi, 1); }
#pragma unroll
    for (int nj = 0; nj < 2; ++nj) { bl[nj][0] = rdB(c, 0, nj, 0); bl[nj][1] = rdB(c, 0, nj, 1); }
    BARRIER();
    __builtin_amdgcn_s_setprio(1);
#pragma unroll
    for (int mi = 0; mi < 4; ++mi)
#pragma unroll
      for (int nj = 0; nj < 2; ++nj) {
        acc[0][mi][nj] = __builtin_amdgcn_mfma_f32_16x16x32_bf16(a[mi][0], bl[nj][0], acc[0][mi][nj], 0, 0, 0);
        acc[0][mi][nj] = __builtin_amdgcn_mfma_f32_16x16x32_bf16(a[mi][1], bl[nj][1], acc[0][mi][nj], 0, 0, 0);
      }
    __builtin_amdgcn_s_setprio(0);
    BARRIER();
    // ---- ph2: Q01 (reuse a); stage A0(t+2) into freed slot ----
#pragma unroll
    for (int nj = 0; nj < 2; ++nj) { bh[nj][0] = rdB(c, 1, nj, 0); bh[nj][1] = rdB(c, 1, nj, 1); }
    if (pf) stage(c, 0, 0, t + 2);
    BARRIER();
    __builtin_amdgcn_s_setprio(1);
#pragma unroll
    for (int mi = 0; mi < 4; ++mi)
#pragma unroll
      for (int nj = 0; nj < 2; ++nj) {
        acc[1][mi][nj] = __builtin_amdgcn_mfma_f32_16x16x32_bf16(a[mi][0], bh[nj][0], acc[1][mi][nj], 0, 0, 0);
        acc[1][mi][nj] = __builtin_amdgcn_mfma_f32_16x16x32_bf16(a[mi][1], bh[nj][1], acc[1][mi][nj], 0, 0, 0);
      }
    __builtin_amdgcn_s_setprio(0);
    BARRIER();
    // ---- ph3: Q10 (reuse bl); stage B1(t+2) ----
#pragma unroll
    for (int mi = 0; mi < 4; ++mi) { a[mi][0] = rdA(c, 1, mi, 0); a[mi][1] = rdA(c, 1, mi, 1); }
    if (pf) stage(c, 1, 1, t + 2);
    BARRIER();
    __builtin_amdgcn_s_setprio(1);
#pragma unroll
    for (int mi = 0; mi < 4; ++mi)
#pragma unroll
      for (int nj = 0; nj < 2; ++nj) {
        acc[2][mi][nj] = __builtin_amdgcn_mfma_f32_16x16x32_bf16(a[mi][0], bl[nj][0], acc[2][mi][nj], 0, 0, 0);
        acc[2][mi][nj] = __builtin_amdgcn_mfma_f32_16x16x32_bf16(a[mi][1], bl[nj][1], acc[2][mi][nj], 0, 0, 0);
      }
    __builtin_amdgcn_s_setprio(0);
    BARRIER();
    // ---- ph4: Q11 (reuse a, bh); stage B0,A1(t+2); single counted wait ----
    if (pf) { stage(c, 1, 0, t + 2); stage(c, 0, 1, t + 2); }
    __builtin_amdgcn_s_setprio(1);
#pragma unroll
    for (int mi = 0; mi < 4; ++mi)
#pragma unroll
      for (int nj = 0; nj < 2; ++nj) {
        acc[3][mi][nj] = __builtin_amdgcn_mfma_f32_16x16x32_bf16(a[mi][0], bh[nj][0], acc[3][mi][nj], 0, 0, 0);
        acc[3][mi][nj] = __builtin_amdgcn_mfma_f32_16x16x32_bf16(a[mi][1], bh[nj][1], acc[3][mi][nj], 0, 0, 0);
      }
    __builtin_amdgcn_s_setprio(0);
    if (vm == 8)      asm volatile("s_waitcnt vmcnt(8)" ::: "memory");
    else if (vm == 0) asm volatile("s_waitcnt vmcnt(0)" ::: "memory");
    BARRIER();
  };

  // prologue: tile0 {A0,B0,B1,A1}, tile1 in steady-state order {A0,B1,B0,A1};
  // vmcnt(8) retires exactly tile0's batch.
  stage(0, 0, 0, 0); stage(0, 1, 0, 0); stage(0, 1, 1, 0); stage(0, 0, 1, 0);
  stage(1, 0, 0, 1); stage(1, 1, 1, 1); stage(1, 1, 0, 1); stage(1, 0, 1, 1);
  asm volatile("s_waitcnt vmcnt(8)" ::: "memory");
  BARRIER();

  for (int t = 0; t < NT - 2; ++t) kstep(t, 1, 8);
  kstep(NT - 2, 0, 0);
  kstep(NT - 1, 0, -1);

  // epilogue: + b1, relu, h1 bf16 [p][4096][256]
  const int rg = lane >> 4;
#pragma unroll
  for (int qh = 0; qh < 2; ++qh)
#pragma unroll
    for (int qv = 0; qv < 2; ++qv) {
      const int qq = qh * 2 + qv;
#pragma unroll
      for (int nj = 0; nj < 2; ++nj) {
        const int col = qv * 128 + sc + nj * 16 + l15;
        const float bb = b1[p * 256 + col];
#pragma unroll
        for (int mi = 0; mi < 4; ++mi) {
          const int rbase = m0 + qh * 128 + sr + mi * 16 + rg * 4;
#pragma unroll
          for (int rr = 0; rr < 4; ++rr) {
            float v = acc[qq][mi][nj][rr] + bb;
            v = v > 0.f ? v : 0.f;
            h1[((size_t)p * 4096 + rbase + rr) * 256 + col] = f2bf(v);
          }
        }
      }
    }
}

// ---------------- GEMM2+3 fused ----------------
__global__ __launch_bounds__(256, 2) void k_gemm23(
    const unsigned short* __restrict__ h1,   // [29][4096][256] bf16
    const unsigned short* __restrict__ W2t,  // [29][128][256] bf16
    const float* __restrict__ b2,
    const float* __restrict__ W3,
    const float* __restrict__ b3,
    float* __restrict__ out) {               // [4096][29]
  __shared__ __align__(16) unsigned short lds_a[128 * 64];
  __shared__ __align__(16) unsigned short lds_b[128 * 64];
  const int tid = threadIdx.x;
  const int lane = tid & 63;
  const int wave = tid >> 6;
  const int m0 = blockIdx.x * 128;
  const int p = blockIdx.y;

  const unsigned short* Ab = h1 + ((size_t)p * 4096 + m0) * 256;
  const unsigned short* Bb = W2t + (size_t)p * 128 * 256;

  f32x4 acc[2][8] = {};

  for (int k0 = 0; k0 < 256; k0 += 64) {
    __syncthreads();
#pragma unroll
    for (int i = 0; i < 4; ++i) {
      int t = i * 256 + tid;
      int r = t >> 3;
      int uu = (t & 7) ^ (r & 7);
      gload16(Ab + (size_t)r * 256 + k0 + uu * 8, &lds_a[(i * 256 + wave * 64) * 8]);
      gload16(Bb + (size_t)r * 256 + k0 + uu * 8, &lds_b[(i * 256 + wave * 64) * 8]);
    }
    __syncthreads();
#pragma unroll
    for (int kk = 0; kk < 64; kk += 32) {
      const int ku = (kk >> 3) + (lane >> 4);
      bf16x8 af[2], bfv[8];
#pragma unroll
      for (int mi = 0; mi < 2; ++mi) {
        int row = wave * 32 + mi * 16 + (lane & 15);
        int u = ku ^ (row & 7);
        af[mi] = __builtin_bit_cast(bf16x8, *(const short8_t*)&lds_a[row * 64 + u * 8]);
      }
#pragma unroll
      for (int nj = 0; nj < 8; ++nj) {
        int row = nj * 16 + (lane & 15);
        int u = ku ^ (row & 7);
        bfv[nj] = __builtin_bit_cast(bf16x8, *(const short8_t*)&lds_b[row * 64 + u * 8]);
      }
#pragma unroll
      for (int mi = 0; mi < 2; ++mi)
#pragma unroll
        for (int nj = 0; nj < 8; ++nj)
          acc[mi][nj] = __builtin_amdgcn_mfma_f32_16x16x32_bf16(af[mi], bfv[nj], acc[mi][nj], 0, 0, 0);
    }
  }

  float b2v[8], w3v[8];
  const int c16 = lane & 15;
#pragma unroll
  for (int nj = 0; nj < 8; ++nj) {
    int c = nj * 16 + c16;
    b2v[nj] = b2[p * 128 + c];
    w3v[nj] = W3[p * 128 + c];
  }
  const float b3p = b3[p];
#pragma unroll
  for (int mi = 0; mi < 2; ++mi) {
#pragma unroll
    for (int r = 0; r < 4; ++r) {
      float s = 0.f;
#pragma unroll
      for (int nj = 0; nj < 8; ++nj) {
        float v = acc[mi][nj][r] + b2v[nj];
        v = v > 0.f ? v : 0.f;
        s += v * w3v[nj];
      }
      s += __shfl_xor(s, 1);
      s += __shfl_xor(s, 2);
      s += __shfl_xor(s, 4);
      s += __shfl_xor(s, 8);
      if ((lane & 15) == 0) {
        int m = m0 + wave * 32 + mi * 16 + (lane >> 4) * 4 + r;
        float logit = s + b3p;
        out[(size_t)m * 29 + p] = 1.f / (1.f + __expf(-logit));
      }
    }
  }
}

// ---------------- launch ----------------
extern "C" void kernel_launch(void* const* d_in, const int* in_sizes, int n_in,
                              void* d_out, int out_size, void* d_ws, size_t ws_size,
                              hipStream_t stream) {
  const float* features = (const float*)d_in[0];
  const float* W1 = (const float*)d_in[1];
  const float* b1 = (const float*)d_in[2];
  const float* W2 = (const float*)d_in[3];
  const float* b2 = (const float*)d_in[4];
  const float* W3 = (const float*)d_in[5];
  const float* b3 = (const float*)d_in[6];
  float* out = (float*)d_out;

  char* ws = (char*)d_ws;
  const size_t featB = (size_t)4096 * 8192 * 2;       // 64 MB
  const size_t h1B   = (size_t)29 * 4096 * 256 * 2;   // 58 MB
  const size_t w2B   = (size_t)29 * 128 * 256 * 2;    // 1.9 MB
  const size_t w1pp  = (size_t)256 * 8192 * 2;        // 4 MB per predicate

  unsigned short* featbf = (unsigned short*)ws;
  unsigned short* h1bf   = (unsigned short*)(ws + featB);
  unsigned short* w2t    = (unsigned short*)(ws + featB + h1B);
  unsigned short* w1t    = (unsigned short*)(ws + featB + h1B + w2B);

  size_t base = featB + h1B + w2B;
  size_t rem = (ws_size > base) ? (ws_size - base) : 0;
  int CH = (int)(rem / w1pp);
  if (CH > 29) CH = 29;
  if (CH < 1) CH = 1;

  k_cvt_feat<<<2048, 256, 0, stream>>>(features, featbf);
  k_cvt_w2<<<29, 256, 0, stream>>>(W2, w2t);

  for (int p0 = 0; p0 < 29; p0 += CH) {
    int c = (29 - p0) < CH ? (29 - p0) : CH;
    k_cvt_w1<<<dim3(128, 4, c), 256, 0, stream>>>(W1, w1t, p0);
    k_gemm1<<<dim3(16, c), 512, 0, stream>>>(featbf, w1t, b1, h1bf, p0);
  }

  k_gemm23<<<dim3(32, 29), 256, 0, stream>>>(h1bf, w2t, b2, W3, b3, out);
}